// Round 10
// baseline (30.975 us; speedup 1.0000x reference)
//
#include <hip/hip_runtime.h>

typedef __attribute__((ext_vector_type(2))) float f2;
typedef __attribute__((ext_vector_type(4))) float f4;

constexpr int KSZ     = 16;
constexpr int STRIDE  = 4;
constexpr int NROWS   = 4096;
constexpr int LCOLS   = 8192;
constexpr int OUT_LEN = (LCOLS - KSZ) / STRIDE + 1;  // 2045
constexpr int BLOCK   = 512;
constexpr int NF4     = LCOLS / 4;                   // 2048 float4 per row

// Involution XOR swizzle on float4 index (r5-proven conflict-free for the
// consecutive-write and 4t-strided-read patterns; shift s only rotates the
// pattern uniformly across the wave).
__device__ __forceinline__ int swz(int q) {
    return q ^ (((q >> 3) ^ (q >> 6)) & 7);
}

__device__ __forceinline__ float softmax_dot(const float* win, const f2* w2)
{
    f2 se2 = {0.f, 0.f}, sr2 = {0.f, 0.f};
#pragma unroll
    for (int kk = 0; kk < KSZ / 2; ++kk) {
        const f2 v  = *reinterpret_cast<const f2*>(win + 2 * kk);
        const f2 tt = v * w2[kk];                   // v_pk_mul_f32
        f2 e;
        e.x = __builtin_amdgcn_exp2f(tt.x);
        e.y = __builtin_amdgcn_exp2f(tt.y);
        se2 += e;                                    // v_pk_add_f32
        sr2 += tt * e;                               // v_pk_fma_f32
    }
    const float se = se2.x + se2.y;
    const float sr = sr2.x + sr2.y;
    return sr * 0.69314718056f * __builtin_amdgcn_rcpf(se);
}

__global__ __launch_bounds__(BLOCK) void or_conv_kernel(
    const float* __restrict__ x, const float* __restrict__ w,
    float* __restrict__ out)
{
    __shared__ float4 smem[NF4];   // 32 KB: one full input row

    const int t = threadIdx.x;
    const int n = blockIdx.x;
    // Row base byte = 8180n; shift s makes output index s+4t 16B-aligned.
    const int s = (4 - (n & 3)) & 3;

    // Weight pairs pre-scaled by log2(e): exp(rho)=exp2(rho*log2e);
    // Σ rho·e = ln2 · Σ tt·e.
    f2 w2[KSZ / 2];
#pragma unroll
    for (int k = 0; k < KSZ / 2; ++k) {
        w2[k].x = w[2 * k]     * 1.44269504089f;
        w2[k].y = w[2 * k + 1] * 1.44269504089f;
    }

    // Stage row -> LDS (r5 path; r6 showed global_load_lds regresses here).
    const float4* rowp4 = reinterpret_cast<const float4*>(x + (size_t)n * LCOLS);
#pragma unroll
    for (int j = 0; j < 4; ++j) {
        const int pos = t + BLOCK * j;          // covers 0..2047 exactly
        smem[swz(pos)] = rowp4[pos];
    }
    __syncthreads();

    // Thread t: 4 consecutive outputs o0..o0+3 (o0 = s+4t), windows span
    // float4 positions o0..o0+6 -> 7 ds_read_b128.
    const int o0 = s + 4 * t;
    float4 f[7];
#pragma unroll
    for (int j = 0; j < 7; ++j) {
        const int q = min(o0 + j, NF4 - 1);     // clamp tail
        f[j] = smem[swz(q)];
    }
    const float* win = reinterpret_cast<const float*>(f);  // 28 floats

    f4 res;
    res.x = softmax_dot(win + 0,          w2);
    res.y = softmax_dot(win + STRIDE,     w2);
    res.z = softmax_dot(win + 2 * STRIDE, w2);
    res.w = softmax_dot(win + 3 * STRIDE, w2);

    float* orow = out + (size_t)n * OUT_LEN;
    if (o0 + 3 <= OUT_LEN - 1) {
        // 16B-aligned, wave-contiguous full-line store -> nontemporal safe
        // (keeps output stream from evicting L3-resident input).
        __builtin_nontemporal_store(res, reinterpret_cast<f4*>(orow + o0));
    } else {
        // Partial tail thread: cached dword stores (lane-scatter, rare).
        const float rr[4] = {res.x, res.y, res.z, res.w};
#pragma unroll
        for (int i = 0; i < 4; ++i)
            if (o0 + i < OUT_LEN) orow[o0 + i] = rr[i];
    }

    // Head outputs 0..s-1 (<=3 per row): threads t<s compute one extra.
    if (t < s) {
        float4 g[4];
#pragma unroll
        for (int j = 0; j < 4; ++j) g[j] = smem[swz(t + j)];
        const float* hwin = reinterpret_cast<const float*>(g);
        orow[t] = softmax_dot(hwin, w2);
    }
}

extern "C" void kernel_launch(void* const* d_in, const int* in_sizes, int n_in,
                              void* d_out, int out_size, void* d_ws, size_t ws_size,
                              hipStream_t stream)
{
    const float* x = (const float*)d_in[0];
    const float* w = (const float*)d_in[1];
    float* out     = (float*)d_out;

    or_conv_kernel<<<dim3(NROWS), dim3(BLOCK), 0, stream>>>(x, w, out);
}

// Round 11
// 30.258 us; speedup vs baseline: 1.0237x; 1.0237x over previous
//
#include <hip/hip_runtime.h>

typedef __attribute__((ext_vector_type(2))) float f2;

constexpr int KSZ     = 16;
constexpr int STRIDE  = 4;
constexpr int NROWS   = 4096;
constexpr int LCOLS   = 8192;
constexpr int OUT_LEN = (LCOLS - KSZ) / STRIDE + 1;  // 2045
constexpr int BLOCK   = 512;
constexpr int NF4     = LCOLS / 4;                   // 2048 float4 per row

// Involution XOR swizzle on float4 index (r5-proven: conflict-free on both
// the consecutive-write and 4t-strided-read patterns).
__device__ __forceinline__ int swz(int q) {
    return q ^ (((q >> 3) ^ (q >> 6)) & 7);
}

__global__ __launch_bounds__(BLOCK) void or_conv_kernel(
    const float* __restrict__ x, const float* __restrict__ w,
    float* __restrict__ out)
{
    __shared__ float4 smem[NF4];   // 32 KB: one full input row

    const int t = threadIdx.x;
    const int n = blockIdx.x;

    // Weight pairs pre-scaled by log2(e): exp(rho)=exp2(rho*log2e);
    // Σ rho·e = ln2 · Σ tt·e.
    f2 w2[KSZ / 2];
#pragma unroll
    for (int k = 0; k < KSZ / 2; ++k) {
        w2[k].x = w[2 * k]     * 1.44269504089f;
        w2[k].y = w[2 * k + 1] * 1.44269504089f;
    }

    // Stage row -> LDS (r5 path: plain ds_write; r6 showed global_load_lds
    // is a regression here). 4 lane-contiguous float4 loads, 1x L1 traffic.
    const float4* rowp4 = reinterpret_cast<const float4*>(x + (size_t)n * LCOLS);
#pragma unroll
    for (int j = 0; j < 4; ++j) {
        const int pos = t + BLOCK * j;          // covers 0..2047 exactly
        smem[swz(pos)] = rowp4[pos];
    }
    __syncthreads();

    // Thread t: 4 consecutive outputs 4t..4t+3, windows span float4
    // positions 4t..4t+6 -> 7 ds_read_b128.
    float4 f[7];
#pragma unroll
    for (int j = 0; j < 7; ++j) {
        const int q = min(4 * t + j, NF4 - 1);  // clamp tail (thread 511)
        f[j] = smem[swz(q)];
    }
    const float* win = reinterpret_cast<const float*>(f);  // 28 floats

    // Packed-f32 math: window pairs are 8B-aligned (start 4i even), so the
    // mul/add/fma stream maps to v_pk_{mul,add,fma}_f32 (VOP3P) - half the
    // VALU instructions. exp2 stays scalar (no packed trans pipe).
    float res[4];
#pragma unroll
    for (int i = 0; i < 4; ++i) {
        f2 se2 = {0.f, 0.f}, sr2 = {0.f, 0.f};
#pragma unroll
        for (int kk = 0; kk < KSZ / 2; ++kk) {
            const f2 v  = *reinterpret_cast<const f2*>(win + STRIDE * i + 2 * kk);
            const f2 tt = v * w2[kk];                       // v_pk_mul_f32
            f2 e;
            e.x = __builtin_amdgcn_exp2f(tt.x);
            e.y = __builtin_amdgcn_exp2f(tt.y);
            se2 += e;                                        // v_pk_add_f32
            sr2 += tt * e;                                   // v_pk_fma_f32
        }
        const float se = se2.x + se2.y;
        const float sr = sr2.x + sr2.y;
        res[i] = sr * 0.69314718056f * __builtin_amdgcn_rcpf(se);
    }

    // 4 consecutive dword stores, NORMAL cached (round-2 lesson:
    // nontemporal lane-scatter = partial-line RMW; r10 lesson: aligned f4
    // NT store is also null-to-negative).
    float* op = out + (size_t)n * OUT_LEN + 4 * t;
#pragma unroll
    for (int i = 0; i < 4; ++i) {
        if (4 * t + i < OUT_LEN) op[i] = res[i];
    }
}

extern "C" void kernel_launch(void* const* d_in, const int* in_sizes, int n_in,
                              void* d_out, int out_size, void* d_ws, size_t ws_size,
                              hipStream_t stream)
{
    const float* x = (const float*)d_in[0];
    const float* w = (const float*)d_in[1];
    float* out     = (float*)d_out;

    or_conv_kernel<<<dim3(NROWS), dim3(BLOCK), 0, stream>>>(x, w, out);
}